// Round 1
// 627.849 us; speedup vs baseline: 1.0176x; 1.0176x over previous
//
#include <hip/hip_runtime.h>
#include <stdint.h>

typedef __bf16 bf16_t;
typedef __bf16 bf16x8 __attribute__((ext_vector_type(8)));
typedef __bf16 bf16x4 __attribute__((ext_vector_type(4)));
typedef float f32x4 __attribute__((ext_vector_type(4)));

// Async global->LDS, 16B per lane (wave-uniform base + lane*16).
#define GLOAD16(gp, lp)                                                        \
    __builtin_amdgcn_global_load_lds(                                          \
        (const __attribute__((address_space(1))) void*)(gp),                   \
        (__attribute__((address_space(3))) void*)(lp), 16, 0, 0)

#define MFMA16(a, b, c) __builtin_amdgcn_mfma_f32_16x16x32_bf16(a, b, c, 0, 0, 0)

// Phase framing: raw s_barrier as inline asm with "memory" clobber so no
// LDS read / stage can cross a phase boundary (compiler-level fence), then
// lgkmcnt(0) + sched_barrier(0) (rule: MFMA must not hoist past the wait),
// setprio(1) around the MFMA cluster (T5).
#define PH_PRE()                                                               \
    do {                                                                       \
        __builtin_amdgcn_sched_barrier(0);                                     \
        asm volatile("s_barrier" ::: "memory");                                \
        asm volatile("s_waitcnt lgkmcnt(0)" ::: "memory");                     \
        __builtin_amdgcn_sched_barrier(0);                                     \
        __builtin_amdgcn_s_setprio(1);                                         \
    } while (0)
#define PH_POST()                                                              \
    do {                                                                       \
        __builtin_amdgcn_s_setprio(0);                                         \
        __builtin_amdgcn_sched_barrier(0);                                     \
        asm volatile("s_barrier" ::: "memory");                                \
    } while (0)

// BK=64 LDS tiles: row = 64 bf16 = 128 B = exactly 32 banks; chunk c of row
// r lives in slot c ^ (r&7) (pre-swizzled global source, linear LDS dest —
// the only layout global_load_lds supports). Readers XOR the same way.

// ---------------------------------------------------------------------------
// All fp32 -> bf16 conversions in ONE launch (7 segments).  (unchanged)
// ---------------------------------------------------------------------------
__global__ __launch_bounds__(256) void cvt_all_kernel(
    const float* __restrict__ x, const float* __restrict__ Wgu,
    const float* __restrict__ Bgu, const float* __restrict__ Wd,
    const float* __restrict__ Bd, const float* __restrict__ Agu,
    const float* __restrict__ Ad, bf16_t* __restrict__ X1,
    bf16_t* __restrict__ W1, bf16_t* __restrict__ W2,
    bf16_t* __restrict__ Abf, bf16_t* __restrict__ Adbf) {
    int b = blockIdx.x;
    const float* src;
    bf16_t* dst;
    int cshift, cmask, ldd, coff, lb;
    if (b < 16384) {
        src = x; dst = X1; cshift = 11; cmask = 2047; ldd = 2112; coff = 0; lb = b;
    } else if (b < 32768) {
        src = Wgu; dst = W1; cshift = 11; cmask = 2047; ldd = 2112; coff = 0; lb = b - 16384;
    } else if (b < 33280) {
        src = Bgu; dst = W1; cshift = 6; cmask = 63; ldd = 2112; coff = 2048; lb = b - 32768;
    } else if (b < 41472) {
        src = Wd; dst = W2; cshift = 12; cmask = 4095; ldd = 4160; coff = 0; lb = b - 33280;
    } else if (b < 41600) {
        src = Bd; dst = W2; cshift = 6; cmask = 63; ldd = 4160; coff = 4096; lb = b - 41472;
    } else if (b < 41728) {
        src = Agu; dst = Abf; cshift = 11; cmask = 2047; ldd = 2048; coff = 0; lb = b - 41600;
    } else {
        src = Ad; dst = Adbf; cshift = 12; cmask = 4095; ldd = 4096; coff = 0; lb = b - 41728;
    }
    int idx = (lb * 256 + threadIdx.x) << 2;
    int r = idx >> cshift;
    int c = idx & cmask;
    float4 v = *(const float4*)(src + idx);
    bf16x4 o = {(bf16_t)v.x, (bf16_t)v.y, (bf16_t)v.z, (bf16_t)v.w};
    *(bf16x4*)(dst + (size_t)r * ldd + coff + c) = o;
}

// ---------------------------------------------------------------------------
// LoRA GEMM (unchanged): t = 0.25 * (A[M x K] @ Bw[64 x K]^T) -> dst cols.
// ---------------------------------------------------------------------------
__global__ __launch_bounds__(256) void lora_kernel(const bf16_t* __restrict__ A,
                                                   int lda,
                                                   const bf16_t* __restrict__ Bw,
                                                   int K, bf16_t* __restrict__ dst,
                                                   int ldd, int coff) {
    __shared__ __align__(16) bf16_t As[64 * 64];
    __shared__ __align__(16) bf16_t Bs[64 * 64];
    const int t = threadIdx.x;
    const int m0 = blockIdx.x * 64;
    const int lane = t & 63, w = t >> 6;
    const int ln15 = lane & 15, q = lane >> 4;

    const int lrow = t >> 3;
    const int lchunk = (t & 7) ^ (lrow & 7);
    const bf16_t* gaL = A + (size_t)(m0 + lrow) * lda + lchunk * 8;
    const bf16_t* gbL = Bw + (size_t)lrow * K + lchunk * 8;
    bf16_t* lA = As + t * 8;
    bf16_t* lB = Bs + t * 8;

    const f32x4 z = {0.f, 0.f, 0.f, 0.f};
    f32x4 acc[4];
#pragma unroll
    for (int j = 0; j < 4; ++j) acc[j] = z;

    int aoffs[2], boffs[2][4];
#pragma unroll
    for (int s = 0; s < 2; ++s) {
        int rowa = w * 16 + ln15;
        aoffs[s] = rowa * 64 + (((q + 4 * s) ^ (rowa & 7)) << 3);
#pragma unroll
        for (int j = 0; j < 4; ++j) {
            int rowb = j * 16 + ln15;
            boffs[s][j] = rowb * 64 + (((q + 4 * s) ^ (rowb & 7)) << 3);
        }
    }

    for (int kt = 0; kt < K; kt += 64) {
        GLOAD16(gaL, lA);
        GLOAD16(gaL + (size_t)32 * lda, lA + 32 * 64);
        GLOAD16(gbL, lB);
        GLOAD16(gbL + (size_t)32 * K, lB + 32 * 64);
        __syncthreads();
#pragma unroll
        for (int s = 0; s < 2; ++s) {
            bf16x8 av = *(const bf16x8*)(As + aoffs[s]);
#pragma unroll
            for (int j = 0; j < 4; ++j) {
                bf16x8 bv = *(const bf16x8*)(Bs + boffs[s][j]);
                acc[j] = MFMA16(av, bv, acc[j]);
            }
        }
        __syncthreads();
        gaL += 64;
        gbL += 64;
    }

#pragma unroll
    for (int j = 0; j < 4; ++j)
#pragma unroll
        for (int rg = 0; rg < 4; ++rg) {
            int m = m0 + w * 16 + q * 4 + rg;
            dst[(size_t)m * ldd + coff + j * 16 + ln15] = (bf16_t)(acc[j][rg] * 0.25f);
        }
}

// ---------------------------------------------------------------------------
// 256x256 8-phase GEMM core (T2 swizzle + T3/T4 counted vmcnt + T5 setprio).
// 512 threads = 8 waves (2M x 4N); per-wave 128x64 output = 8x4 16x16 frags.
// LDS: 2 x (A 256x64 + B 256x64) bf16 = 128 KiB, double-buffered by K-tile
// parity. Per K-tile group, 4 phases (quadrants (0,0),(0,1),(1,1),(1,0)),
// each phase: ds_read changed frags | stage one 2-GLOAD unit | s_barrier |
// lgkmcnt(0) | 16 MFMA | s_barrier.
// Stage schedule (safety: a stage may only target a region whose last
// ds_read issued >= 1 phase earlier):
//   p1: A-half1(g+1) -> other buf   (A1 of buf^1 last read at (g-1)p3)
//   p2: A-half0(g+2) -> this buf    (A0 last read at p1)
//   p3: B rows 0-127 (g+2) -> this  (B last read at p2)
//   p4: B rows 128-255 (g+2) -> this
// One s_waitcnt vmcnt(6) at end of p4 retires everything through p1's
// A1(g+1) (exactly 3 half-tiles = 6 loads stay in flight) -> tile g+1 is
// fully resident before its first read.  Tail: vmcnt(0) when no stages
// follow. A-half0 = rows {0-63,128-191} (read by quadrant qi=0 across both
// wave-row groups), A-half1 = rows {64-127,192-255}.
// ---------------------------------------------------------------------------
template <int LDA_, int LDB_, int NT_>
__device__ __forceinline__ void gemm8p_core(const bf16_t* __restrict__ gA,
                                            const bf16_t* __restrict__ gB0,
                                            const bf16_t* __restrict__ gB2,
                                            bf16_t* smem, const int t,
                                            const int offA0, const int offA1,
                                            const int offB0, const int offB1,
                                            f32x4 (&acc)[8][4]) {
    auto stgA0 = [&](int kt, bf16_t* d) {
        GLOAD16(gA + kt, d + t * 8);
        GLOAD16(gA + (size_t)128 * LDA_ + kt, d + 128 * 64 + t * 8);
    };
    auto stgA1 = [&](int kt, bf16_t* d) {
        GLOAD16(gA + (size_t)64 * LDA_ + kt, d + 64 * 64 + t * 8);
        GLOAD16(gA + (size_t)192 * LDA_ + kt, d + 192 * 64 + t * 8);
    };
    auto stgBlo = [&](int kt, bf16_t* d) {
        GLOAD16(gB0 + kt, d + t * 8);
        GLOAD16(gB0 + (size_t)64 * LDB_ + kt, d + 64 * 64 + t * 8);
    };
    auto stgBhi = [&](int kt, bf16_t* d) {
        GLOAD16(gB2 + kt, d + 128 * 64 + t * 8);
        GLOAD16(gB2 + (size_t)64 * LDB_ + kt, d + 192 * 64 + t * 8);
    };

    bf16_t* const As0 = smem;
    bf16_t* const As1 = smem + 16384;
    bf16_t* const Bs0 = smem + 32768;
    bf16_t* const Bs1 = smem + 49152;

    // prologue: tile0 full (8 loads) -> buf0, tile1 minus A1 (6) -> buf1.
    stgA0(0, As0);
    stgA1(0, As0);
    stgBlo(0, Bs0);
    stgBhi(0, Bs0);
    stgA0(64, As1);
    stgBlo(64, Bs1);
    stgBhi(64, Bs1);
    asm volatile("s_waitcnt vmcnt(6)" ::: "memory");  // tile0 resident
    asm volatile("s_barrier" ::: "memory");

    bf16x8 av[4][2], b0[2][2], b1[2][2];
    for (int g = 0; g < NT_; ++g) {
        const int bs = (g & 1) << 14;
        bf16_t* const Asc = smem + bs;
        bf16_t* const Bsc = smem + 32768 + bs;
        bf16_t* const Asn = smem + (bs ^ 16384);
        const int k1 = (g + 1) << 6, k2 = (g + 2) << 6;

        // ---- phase 1 (qi=0, qj=0): read A0 + B0 frags; stage A1(g+1) ----
#pragma unroll
        for (int m = 0; m < 4; ++m) {
            av[m][0] = *(const bf16x8*)(Asc + offA0 + m * 1024);
            av[m][1] = *(const bf16x8*)(Asc + offA1 + m * 1024);
        }
#pragma unroll
        for (int n = 0; n < 2; ++n) {
            b0[n][0] = *(const bf16x8*)(Bsc + offB0 + n * 1024);
            b0[n][1] = *(const bf16x8*)(Bsc + offB1 + n * 1024);
        }
        if (g + 1 < NT_) stgA1(k1, Asn);
        PH_PRE();
#pragma unroll
        for (int m = 0; m < 4; ++m)
#pragma unroll
            for (int n = 0; n < 2; ++n) {
                acc[m][n] = MFMA16(av[m][0], b0[n][0], acc[m][n]);
                acc[m][n] = MFMA16(av[m][1], b0[n][1], acc[m][n]);
            }
        PH_POST();

        // ---- phase 2 (qi=0, qj=1): read B1 frags; stage A0(g+2) ----
#pragma unroll
        for (int n = 0; n < 2; ++n) {
            b1[n][0] = *(const bf16x8*)(Bsc + offB0 + (2 + n) * 1024);
            b1[n][1] = *(const bf16x8*)(Bsc + offB1 + (2 + n) * 1024);
        }
        if (g + 2 < NT_) stgA0(k2, Asc);
        PH_PRE();
#pragma unroll
        for (int m = 0; m < 4; ++m)
#pragma unroll
            for (int n = 0; n < 2; ++n) {
                acc[m][2 + n] = MFMA16(av[m][0], b1[n][0], acc[m][2 + n]);
                acc[m][2 + n] = MFMA16(av[m][1], b1[n][1], acc[m][2 + n]);
            }
        PH_POST();

        // ---- phase 3 (qi=1, qj=1): read A1 frags; stage Blo(g+2) ----
#pragma unroll
        for (int m = 0; m < 4; ++m) {
            av[m][0] = *(const bf16x8*)(Asc + offA0 + (4 + m) * 1024);
            av[m][1] = *(const bf16x8*)(Asc + offA1 + (4 + m) * 1024);
        }
        if (g + 2 < NT_) stgBlo(k2, Bsc);
        PH_PRE();
#pragma unroll
        for (int m = 0; m < 4; ++m)
#pragma unroll
            for (int n = 0; n < 2; ++n) {
                acc[4 + m][2 + n] = MFMA16(av[m][0], b1[n][0], acc[4 + m][2 + n]);
                acc[4 + m][2 + n] = MFMA16(av[m][1], b1[n][1], acc[4 + m][2 + n]);
            }
        PH_POST();

        // ---- phase 4 (qi=1, qj=0): no reads; stage Bhi(g+2); vmcnt gate ----
        if (g + 2 < NT_) stgBhi(k2, Bsc);
        PH_PRE();
#pragma unroll
        for (int m = 0; m < 4; ++m)
#pragma unroll
            for (int n = 0; n < 2; ++n) {
                acc[4 + m][n] = MFMA16(av[m][0], b0[n][0], acc[4 + m][n]);
                acc[4 + m][n] = MFMA16(av[m][1], b0[n][1], acc[4 + m][n]);
            }
        __builtin_amdgcn_s_setprio(0);
        __builtin_amdgcn_sched_barrier(0);
        if (g + 2 < NT_)
            asm volatile("s_waitcnt vmcnt(6)" ::: "memory");
        else
            asm volatile("s_waitcnt vmcnt(0)" ::: "memory");
        asm volatile("s_barrier" ::: "memory");
    }
}

// ---------------------------------------------------------------------------
// GEMM1 (fused gate_up + SwiGLU), 8-phase: X1[8192x2112] @ [gate|up]^T.
// B-tile rows 0-127 = gate cols n0.., rows 128-255 = up cols n0.. (W rows
// 4096+n0..). Waves wc<2 hold gate, wc>=2 hold up; SwiGLU combined through
// LDS in the epilogue. Output: X2 rows m0..m0+255, cols n0..n0+127.
// ---------------------------------------------------------------------------
__global__ __launch_bounds__(512, 2) void gemm1_8p_kernel(
    const bf16_t* __restrict__ X, const bf16_t* __restrict__ Wc,
    bf16_t* __restrict__ X2) {
    __shared__ __align__(16) bf16_t smem[65536];  // 128 KiB
    const int t = threadIdx.x;
    const int lane = t & 63, wid = t >> 6;
    const int wr = wid >> 2, wc = wid & 3;
    const int ln15 = lane & 15, q = lane >> 4;
    const int n0 = blockIdx.x * 128;
    const int m0 = blockIdx.y * 256;

    const int sw = ln15 & 7;
    const int offA0 = (wr * 128 + ln15) * 64 + ((q ^ sw) << 3);
    const int offA1 = (wr * 128 + ln15) * 64 + (((q + 4) ^ sw) << 3);
    const int offB0 = (wc * 64 + ln15) * 64 + ((q ^ sw) << 3);
    const int offB1 = (wc * 64 + ln15) * 64 + (((q + 4) ^ sw) << 3);

    const int rr = t >> 3;
    const int lch = (t & 7) ^ (rr & 7);
    const bf16_t* gA = X + (size_t)(m0 + rr) * 2112 + lch * 8;
    const bf16_t* gB0 = Wc + (size_t)(n0 + rr) * 2112 + lch * 8;           // gate
    const bf16_t* gB2 = Wc + (size_t)(4096 + n0 + rr) * 2112 + lch * 8;    // up

    f32x4 acc[8][4];
    const f32x4 z = {0.f, 0.f, 0.f, 0.f};
#pragma unroll
    for (int i = 0; i < 8; ++i)
#pragma unroll
        for (int j = 0; j < 4; ++j) acc[i][j] = z;

    gemm8p_core<2112, 2112, 33>(gA, gB0, gB2, smem, t, offA0, offA1, offB0,
                                offB1, acc);

    // Epilogue: up waves park acc in LDS (256x128 f32 = 128 KiB exactly),
    // gate waves read matching up value and apply SwiGLU.
    __syncthreads();
    float* fs = (float*)smem;
    if (wc >= 2) {
#pragma unroll
        for (int mi = 0; mi < 8; ++mi)
#pragma unroll
            for (int nj = 0; nj < 4; ++nj)
#pragma unroll
                for (int rg = 0; rg < 4; ++rg) {
                    int row = wr * 128 + mi * 16 + q * 4 + rg;
                    int col = (wc - 2) * 64 + nj * 16 + ln15;
                    fs[row * 128 + col] = acc[mi][nj][rg];
                }
    }
    __syncthreads();
    if (wc < 2) {
#pragma unroll
        for (int mi = 0; mi < 8; ++mi)
#pragma unroll
            for (int nj = 0; nj < 4; ++nj)
#pragma unroll
                for (int rg = 0; rg < 4; ++rg) {
                    int row = wr * 128 + mi * 16 + q * 4 + rg;
                    int col = wc * 64 + nj * 16 + ln15;
                    float gv = acc[mi][nj][rg];
                    float uv = fs[row * 128 + col];
                    float h = uv * gv / (1.f + __expf(-gv));  // up * silu(gate)
                    X2[(size_t)(m0 + row) * 4160 + (n0 + col)] = (bf16_t)h;
                }
    }
}

// ---------------------------------------------------------------------------
// GEMM2, 8-phase: out = X2[8192x4160] @ Wdc[2048x4160]^T, fp32 out.
// grid (8, 32) = 256 blocks = exactly one round at 1 block/CU.
// ---------------------------------------------------------------------------
__global__ __launch_bounds__(512, 2) void gemm2_8p_kernel(
    const bf16_t* __restrict__ X2, const bf16_t* __restrict__ Wdc,
    float* __restrict__ out) {
    __shared__ __align__(16) bf16_t smem[65536];  // 128 KiB
    const int t = threadIdx.x;
    const int lane = t & 63, wid = t >> 6;
    const int wr = wid >> 2, wc = wid & 3;
    const int ln15 = lane & 15, q = lane >> 4;
    const int n0 = blockIdx.x * 256;
    const int m0 = blockIdx.y * 256;

    const int sw = ln15 & 7;
    const int offA0 = (wr * 128 + ln15) * 64 + ((q ^ sw) << 3);
    const int offA1 = (wr * 128 + ln15) * 64 + (((q + 4) ^ sw) << 3);
    const int offB0 = (wc * 64 + ln15) * 64 + ((q ^ sw) << 3);
    const int offB1 = (wc * 64 + ln15) * 64 + (((q + 4) ^ sw) << 3);

    const int rr = t >> 3;
    const int lch = (t & 7) ^ (rr & 7);
    const bf16_t* gA = X2 + (size_t)(m0 + rr) * 4160 + lch * 8;
    const bf16_t* gB0 = Wdc + (size_t)(n0 + rr) * 4160 + lch * 8;
    const bf16_t* gB2 = Wdc + (size_t)(n0 + 128 + rr) * 4160 + lch * 8;

    f32x4 acc[8][4];
    const f32x4 z = {0.f, 0.f, 0.f, 0.f};
#pragma unroll
    for (int i = 0; i < 8; ++i)
#pragma unroll
        for (int j = 0; j < 4; ++j) acc[i][j] = z;

    gemm8p_core<4160, 4160, 65>(gA, gB0, gB2, smem, t, offA0, offA1, offB0,
                                offB1, acc);

#pragma unroll
    for (int mi = 0; mi < 8; ++mi)
#pragma unroll
        for (int nj = 0; nj < 4; ++nj)
#pragma unroll
            for (int rg = 0; rg < 4; ++rg) {
                int row = wr * 128 + mi * 16 + q * 4 + rg;
                int col = wc * 64 + nj * 16 + ln15;
                out[(size_t)(m0 + row) * 2048 + (n0 + col)] = acc[mi][nj][rg];
            }
}

// ---------------------------------------------------------------------------
// Workspace layout (bytes):
//   X1   @ 0         : 8192 x 2112 bf16   [x | 0.25*x@A_gu^T]
//   W1   @ 34603008  : 8192 x 2112 bf16   [W_gu | B_gu]
//   X2   @ 69206016  : 8192 x 4160 bf16   [h | 0.25*h@A_d^T]
//   W2   @ 137363456 : 2048 x 4160 bf16   [W_d | B_d]
//   Abf  @ 154402816 : 64 x 2048 bf16
//   Adbf @ 154664960 : 64 x 4096 bf16
// ---------------------------------------------------------------------------
extern "C" void kernel_launch(void* const* d_in, const int* in_sizes, int n_in,
                              void* d_out, int out_size, void* d_ws, size_t ws_size,
                              hipStream_t stream) {
    const float* x = (const float*)d_in[0];
    const float* Wgu = (const float*)d_in[1];
    const float* Agu = (const float*)d_in[2];
    const float* Bgu = (const float*)d_in[3];
    const float* Wd = (const float*)d_in[4];
    const float* Ad = (const float*)d_in[5];
    const float* Bd = (const float*)d_in[6];
    float* out = (float*)d_out;

    char* ws = (char*)d_ws;
    bf16_t* X1 = (bf16_t*)(ws);
    bf16_t* W1 = (bf16_t*)(ws + 34603008);
    bf16_t* X2 = (bf16_t*)(ws + 69206016);
    bf16_t* W2 = (bf16_t*)(ws + 137363456);
    bf16_t* Abf = (bf16_t*)(ws + 154402816);
    bf16_t* Adbf = (bf16_t*)(ws + 154664960);

    // all fp32 -> bf16 conversions, single launch
    cvt_all_kernel<<<41984, 256, 0, stream>>>(x, Wgu, Bgu, Wd, Bd, Agu, Ad,
                                              X1, W1, W2, Abf, Adbf);

    // t1 = 0.25 * x @ A_gu^T  -> X1 cols [2048,2112)
    lora_kernel<<<128, 256, 0, stream>>>(X1, 2112, Abf, 2048, X1, 2112, 2048);
    // fused gate_up GEMM + SwiGLU -> X2 cols [0,4096)   (256x256 8-phase)
    gemm1_8p_kernel<<<dim3(32, 32), 512, 0, stream>>>(X1, W1, X2);
    // t2 = 0.25 * h @ A_d^T -> X2 cols [4096,4160)
    lora_kernel<<<128, 256, 0, stream>>>(X2, 4160, Adbf, 4096, X2, 4160, 4096);
    // out = X2 @ [W_d|B_d]^T   (256x256 8-phase)
    gemm2_8p_kernel<<<dim3(8, 32), 512, 0, stream>>>(X2, W2, out);
}